// Round 2
// 669.336 us; speedup vs baseline: 1.0201x; 1.0201x over previous
//
#include <hip/hip_runtime.h>
#include <hip/hip_bf16.h>

#define NN 8
#define CC 128
#define HH 128
#define WW 128
#define HWP (HH*WW)
#define KK 7
#define DD 49
#define NPH 31
#define NPATCH 961
#define PHN 19
#define PAD 52
#define PP2 (PAD*PAD)

typedef __attribute__((ext_vector_type(8))) short bf16x8;
typedef __attribute__((ext_vector_type(4))) float f32x4;
typedef __attribute__((ext_vector_type(4))) unsigned short us4;

__device__ __forceinline__ unsigned short f2bf(float f) {
    unsigned u = __builtin_bit_cast(unsigned, f);
    return (unsigned short)((u + 0x7FFFu + ((u >> 16) & 1u)) >> 16);   // RNE
}

// ---------------------------------------------------------------------------
// Fused per-patch attention. Math identical to the passing version (fp32
// GEMMs, same accumulation order). Latency de-serialized:
//  - gather: one f4+f2+f1 row load per (c2,kh) slot, decode amortized 7x
//  - Q gather overlapped with ec GEMM (wave 0 vs waves 1..7.5, wave-aligned)
//  - softmax stats: all 512 threads, 4 partial lanes/line + shfl_xor reduce
//  - mask gates folded into output-GEMM phase on spare threads (one less
//    barrier + serial phase); unneeded mid-ec barrier removed
//  - writeout: row-batched residual loads/stores
// ---------------------------------------------------------------------------
__global__ __launch_bounds__(512, 4) void attn_kernel(
    const float* __restrict__ ex_g, const float* __restrict__ q_g,
    const float* __restrict__ Wce, const float* __restrict__ wg1,
    const float* __restrict__ wg2,
    float* __restrict__ xe, float* __restrict__ xq)
{
    __shared__ float s_ex[CC*PAD];
    __shared__ float s_q [CC*PAD];
    __shared__ float s_scr[CC*PAD];
    __shared__ float s_m1[PAD], s_l1[PAD], s_m2[PAD], s_l2[PAD];
    __shared__ float s_g1[PAD], s_g2[PAD], s_me[PAD], s_mq[PAD];

    const int t  = threadIdx.x;
    const int n  = blockIdx.y;
    const int ph = blockIdx.x / PHN;
    const int pw = blockIdx.x % PHN;
    const int pp = (ph * NPH + pw) * CC;

    const float* exn = ex_g + (size_t)n * CC * HWP;
    const float* qn  = q_g  + (size_t)n * CC * HWP;

    // ---- Phase 1: EX gather. Slot i = (c2, kh): one 7-float row; kh==7 zeroes pad.
    #pragma unroll
    for (int ii = 0; ii < 2; ++ii) {
        const int i  = t + ii*512;
        const int c2 = i >> 3, kh = i & 7;
        const int rem  = pp + c2;
        const int c_u  = rem / NPATCH;
        const int p_u  = rem - c_u * NPATCH;
        const int ph_u = p_u / NPH;
        const int pw_u = p_u - ph_u * NPH;
        float* de = &s_ex[c2*PAD + kh*KK];
        if (kh < KK) {
            const float* se = exn + ((c_u*HH + ph_u*4 + kh)*WW + pw_u*4);
            const float4 e4 = *(const float4*)se;       // 16B aligned (pw_u*4 floats)
            const float2 e2 = *(const float2*)(se + 4);
            const float  e1 = se[6];
            de[0]=e4.x; de[1]=e4.y; de[2]=e4.z; de[3]=e4.w;
            de[4]=e2.x; de[5]=e2.y; de[6]=e1;
        } else {
            de[0]=0.f; de[1]=0.f; de[2]=0.f;            // cols 49..51
        }
    }
    __syncthreads();

    // ---- Phase 2: ec = Wce @ ex on waves 1..7.5 ; Q gather on wave 0.
    if (t >= 64 && t < 480) {
        const int t2 = t - 64;
        const int eg_o = t2 / 13, eg_d = t2 - (t2/13)*13;
        const int o0 = eg_o*4, d0 = eg_d*4;
        float ac[4][4];
        #pragma unroll
        for (int i = 0; i < 4; ++i)
            #pragma unroll
            for (int j = 0; j < 4; ++j) ac[i][j] = 0.f;
        for (int k = 0; k < CC; k += 4) {
            float xm[4][4];
            #pragma unroll
            for (int kk = 0; kk < 4; ++kk) {
                float4 xv = *(const float4*)&s_ex[(k+kk)*PAD + d0];
                xm[kk][0]=xv.x; xm[kk][1]=xv.y; xm[kk][2]=xv.z; xm[kk][3]=xv.w;
            }
            #pragma unroll
            for (int i = 0; i < 4; ++i) {
                float4 wv = *(const float4*)&Wce[(o0+i)*CC + k];
                float wr[4] = {wv.x, wv.y, wv.z, wv.w};
                #pragma unroll
                for (int kk = 0; kk < 4; ++kk)
                    #pragma unroll
                    for (int j = 0; j < 4; ++j)
                        ac[i][j] = fmaf(wr[kk], xm[kk][j], ac[i][j]);
            }
        }
        #pragma unroll
        for (int i = 0; i < 4; ++i)
            *(float4*)&s_scr[(o0+i)*PAD + d0] =
                make_float4(ac[i][0], ac[i][1], ac[i][2], ac[i][3]);
    } else if (t < 64) {
        #pragma unroll 4
        for (int jj = 0; jj < 16; ++jj) {
            const int i  = t + jj*64;                   // covers [0,1024) exactly
            const int c2 = i >> 3, kh = i & 7;
            const int rem  = pp + c2;
            const int c_u  = rem / NPATCH;
            const int p_u  = rem - c_u * NPATCH;
            const int ph_u = p_u / NPH;
            const int pw_u = p_u - ph_u * NPH;
            float* dq = &s_q[c2*PAD + kh*KK];
            if (kh < KK) {
                const float* sq = qn + ((c_u*HH + ph_u*4 + kh)*WW + pw_u*4);
                const float4 q4 = *(const float4*)sq;
                const float2 q2 = *(const float2*)(sq + 4);
                const float  q1 = sq[6];
                dq[0]=q4.x; dq[1]=q4.y; dq[2]=q4.z; dq[3]=q4.w;
                dq[4]=q2.x; dq[5]=q2.y; dq[6]=q1;
            } else {
                dq[0]=0.f; dq[1]=0.f; dq[2]=0.f;
            }
        }
    }
    __syncthreads();

    // ---- Phase 3: A = ec^T q, 338 threads 4d x 2e; g1/g2 on spare threads.
    float aa[4][2];
    int ad0 = 0, ae0 = 0;
    if (t < 338) {
        int dg = t % 13, eg = t / 13;
        ad0 = dg*4; ae0 = eg*2;
        #pragma unroll
        for (int i = 0; i < 4; ++i) { aa[i][0] = 0.f; aa[i][1] = 0.f; }
        #pragma unroll 4
        for (int k = 0; k < CC; ++k) {
            float4 ev = *(const float4*)&s_scr[k*PAD + ad0];
            float2 qv = *(const float2*)&s_q [k*PAD + ae0];
            #pragma unroll
            for (int i = 0; i < 4; ++i) {
                float e = (i==0)?ev.x:(i==1)?ev.y:(i==2)?ev.z:ev.w;
                aa[i][0] = fmaf(e, qv.x, aa[i][0]);
                aa[i][1] = fmaf(e, qv.y, aa[i][1]);
            }
        }
    } else if (t >= 352 && t < 352 + DD) {
        int e = t - 352;
        float acc = 0.f;
        for (int c = 0; c < CC; ++c) acc = fmaf(wg1[c], s_q[c*PAD + e], acc);
        s_g1[e] = acc;
    } else if (t >= 416 && t < 416 + DD) {
        int d = t - 416;
        float acc = 0.f;
        for (int c = 0; c < CC; ++c) acc = fmaf(wg2[c], s_ex[c*PAD + d], acc);
        s_g2[d] = acc;
    }
    __syncthreads();
    if (t < 338) {
        #pragma unroll
        for (int i = 0; i < 4; ++i)
            *(float2*)&s_scr[(ad0+i)*PAD + ae0] = make_float2(aa[i][0], aa[i][1]);
    }
    __syncthreads();

    // ---- Phase 4: softmax stats, 4 partial lanes per line, shfl_xor reduce.
    {
        const int sub  = t & 3;
        const int line = (t >> 2) & 63;
        const int lo   = sub * 13;
        float v[13];
        if (t < 256) {                      // set 1: per column e, over d
            if (line < DD) {
                #pragma unroll
                for (int j = 0; j < 13; ++j) {
                    int d = lo + j;
                    v[j] = (d < DD) ? s_scr[d*PAD + line] : -1e30f;
                }
                float m = v[0];
                #pragma unroll
                for (int j = 1; j < 13; ++j) m = fmaxf(m, v[j]);
                m = fmaxf(m, __shfl_xor(m, 1));
                m = fmaxf(m, __shfl_xor(m, 2));
                float l = 0.f;
                #pragma unroll
                for (int j = 0; j < 13; ++j) l += __expf(v[j] - m);  // sentinel -> 0
                l += __shfl_xor(l, 1);
                l += __shfl_xor(l, 2);
                if (sub == 0) { s_m1[line] = m; s_l1[line] = 1.f / l; }
            } else if (line < PAD && sub == 0) { s_m1[line] = 0.f; s_l1[line] = 0.f; }
        } else {                            // set 2: per row d, over e
            if (line < DD) {
                #pragma unroll
                for (int j = 0; j < 13; ++j) {
                    int e = lo + j;
                    v[j] = (e < DD) ? s_scr[line*PAD + e] : -1e30f;
                }
                float m = v[0];
                #pragma unroll
                for (int j = 1; j < 13; ++j) m = fmaxf(m, v[j]);
                m = fmaxf(m, __shfl_xor(m, 1));
                m = fmaxf(m, __shfl_xor(m, 2));
                float l = 0.f;
                #pragma unroll
                for (int j = 0; j < 13; ++j) l += __expf(v[j] - m);
                l += __shfl_xor(l, 1);
                l += __shfl_xor(l, 2);
                if (sub == 0) { s_m2[line] = m; s_l2[line] = 1.f / l; }
            } else if (line < PAD && sub == 0) { s_m2[line] = 0.f; s_l2[line] = 0.f; }
        }
    }
    __syncthreads();

    // ---- Phase 5: P build: P1[d][e] upper scr; P2T[e][d] in-place via snapshot.
    float* P1  = s_scr + PP2;
    float* P2T = s_scr;
    {
        float p2buf[6]; int nv = 0;
        for (int i = t; i < PP2; i += 512) {
            int d = i / PAD, e = i - d*PAD;
            float a = s_scr[i];
            P1[i] = __expf(a - s_m1[e]) * s_l1[e];
            p2buf[nv++] = __expf(a - s_m2[d]) * s_l2[d];
        }
        __syncthreads();
        nv = 0;
        for (int i = t; i < PP2; i += 512) {
            int d = i / PAD, e = i - d*PAD;
            P2T[e*PAD + d] = p2buf[nv++];
        }
    }
    __syncthreads();

    // ---- Phase 6: output GEMMs (416 thr) ; mask gates on the 96 spares.
    float ae_[4][4], aq_[4][4];
    int c0 = 0, x0 = 0;
    if (t < 416) {
        int cg = t / 13, xg = t - (t/13)*13;
        c0 = cg*4; x0 = xg*4;
        #pragma unroll
        for (int i = 0; i < 4; ++i)
            #pragma unroll
            for (int j = 0; j < 4; ++j) { ae_[i][j] = 0.f; aq_[i][j] = 0.f; }
        for (int k = 0; k < 48; k += 4) {
            float qm[4][4], xm[4][4], p1m[4][4], p2m[4][4];
            #pragma unroll
            for (int i = 0; i < 4; ++i) {
                float4 qv = *(const float4*)&s_q [(c0+i)*PAD + k];
                float4 xv = *(const float4*)&s_ex[(c0+i)*PAD + k];
                qm[i][0]=qv.x; qm[i][1]=qv.y; qm[i][2]=qv.z; qm[i][3]=qv.w;
                xm[i][0]=xv.x; xm[i][1]=xv.y; xm[i][2]=xv.z; xm[i][3]=xv.w;
            }
            #pragma unroll
            for (int kk = 0; kk < 4; ++kk) {
                float4 p1 = *(const float4*)&P1 [(k+kk)*PAD + x0];
                float4 p2 = *(const float4*)&P2T[(k+kk)*PAD + x0];
                p1m[kk][0]=p1.x; p1m[kk][1]=p1.y; p1m[kk][2]=p1.z; p1m[kk][3]=p1.w;
                p2m[kk][0]=p2.x; p2m[kk][1]=p2.y; p2m[kk][2]=p2.z; p2m[kk][3]=p2.w;
            }
            #pragma unroll
            for (int kk = 0; kk < 4; ++kk)
                #pragma unroll
                for (int i = 0; i < 4; ++i)
                    #pragma unroll
                    for (int j = 0; j < 4; ++j) {
                        ae_[i][j] = fmaf(qm[i][kk], p2m[kk][j], ae_[i][j]);
                        aq_[i][j] = fmaf(xm[i][kk], p1m[kk][j], aq_[i][j]);
                    }
        }
        {
            const int k = 48;
            float p1r[4], p2r[4];
            #pragma unroll
            for (int j = 0; j < 4; ++j) { p1r[j] = P1 [k*PAD + x0 + j];
                                          p2r[j] = P2T[k*PAD + x0 + j]; }
            #pragma unroll
            for (int i = 0; i < 4; ++i) {
                float qv = s_q [(c0+i)*PAD + k];
                float xv = s_ex[(c0+i)*PAD + k];
                #pragma unroll
                for (int j = 0; j < 4; ++j) {
                    ae_[i][j] = fmaf(qv, p2r[j], ae_[i][j]);
                    aq_[i][j] = fmaf(xv, p1r[j], aq_[i][j]);
                }
            }
        }
    } else {
        const int u = t - 416;
        if (u < DD) {
            float a1 = 0.f;
            for (int e = 0; e < DD; ++e) a1 = fmaf(s_g1[e], P2T[e*PAD + u], a1);
            s_me[u] = 1.f / (1.f + __expf(-a1));
            if (u < 2) {                                 // cover mq[47], mq[48]
                const int e2 = DD - 2 + u;
                float a2 = 0.f;
                for (int d = 0; d < DD; ++d) a2 = fmaf(s_g2[d], P1[d*PAD + e2], a2);
                s_mq[e2] = 1.f / (1.f + __expf(-a2));
            }
        } else {
            const int e2 = u - DD;                       // 0..46
            float a2 = 0.f;
            for (int d = 0; d < DD; ++d) a2 = fmaf(s_g2[d], P1[d*PAD + e2], a2);
            s_mq[e2] = 1.f / (1.f + __expf(-a2));
        }
    }
    __syncthreads();
    if (t < 416) {
        #pragma unroll
        for (int i = 0; i < 4; ++i) {
            *(float4*)&s_ex[(c0+i)*PAD + x0] =
                make_float4(ae_[i][0], ae_[i][1], ae_[i][2], ae_[i][3]);
            *(float4*)&s_q [(c0+i)*PAD + x0] =
                make_float4(aq_[i][0], aq_[i][1], aq_[i][2], aq_[i][3]);
        }
    }
    __syncthreads();

    // ---- Phase 7: writeout, one 7-px row per slot; residual loads batched.
    {
        const size_t nbase = (size_t)n * CC * HWP;
        const int hb = ph*KK, wb = pw*KK;
        const int wlim = (WW - wb) < KK ? (WW - wb) : KK;
        #pragma unroll
        for (int ii = 0; ii < 2; ++ii) {
            const int i  = t + ii*512;
            const int c  = i >> 3, kh = i & 7;
            const int h  = hb + kh;
            if (kh < KK && h < HH) {
                const int li = (c*HH + h)*WW + wb;
                const float* sxe = &s_ex[c*PAD + kh*KK];
                const float* sxq = &s_q [c*PAD + kh*KK];
                if (wlim == KK) {
                    #pragma unroll
                    for (int kw = 0; kw < KK; ++kw) {
                        const int d = kh*KK + kw;
                        xe[nbase + li + kw] = sxe[kw]*s_me[d] + exn[li + kw];
                        xq[nbase + li + kw] = sxq[kw]*s_mq[d] + qn [li + kw];
                    }
                } else {
                    for (int kw = 0; kw < wlim; ++kw) {
                        const int d = kh*KK + kw;
                        xe[nbase + li + kw] = sxe[kw]*s_me[d] + exn[li + kw];
                        xq[nbase + li + kw] = sxq[kw]*s_mq[d] + qn [li + kw];
                    }
                }
            }
        }
    }
}

// ---------------------------------------------------------------------------
// Fused pair of depthwise 3x3 + BN + ReLU. f32 in, bf16 out (pw consumes it).
// ---------------------------------------------------------------------------
__global__ __launch_bounds__(256) void dw2_kernel(
    const float* __restrict__ xA, unsigned short* __restrict__ yA,
    const float* __restrict__ xB, unsigned short* __restrict__ yB,
    const float* __restrict__ wdw, const float* __restrict__ g,
    const float* __restrict__ b, int CoutTot, int coffA, int coffB)
{
    int bid = blockIdx.x;
    int sel = bid >> 12;
    int idx = (bid & 4095) * 256 + threadIdx.x;
    const float* x = sel ? xB : xA;
    unsigned short* y = sel ? yB : yA;
    int coff          = sel ? coffB : coffA;

    int w4 = (idx & 31) * 4;
    int h4 = ((idx >> 5) & 31) * 4;
    int nc = idx >> 10;
    int c  = nc & 127;
    int n  = nc >> 7;

    const float* wp = wdw + (coff + c) * 9;
    float wr[9];
    #pragma unroll
    for (int i = 0; i < 9; ++i) wr[i] = wp[i];

    const float* base = x + (size_t)nc * HWP;
    float acc[4][4];
    #pragma unroll
    for (int i = 0; i < 4; ++i)
        #pragma unroll
        for (int j = 0; j < 4; ++j) acc[i][j] = 0.f;

    #pragma unroll
    for (int r = 0; r < 6; ++r) {
        int hh = h4 - 1 + r;
        if (hh >= 0 && hh < HH) {
            const float* row = base + hh * WW + w4;
            float4 v = *(const float4*)row;
            float e[6];
            e[0] = (w4 > 0)   ? row[-1] : 0.f;
            e[1] = v.x; e[2] = v.y; e[3] = v.z; e[4] = v.w;
            e[5] = (w4 < 124) ? row[4]  : 0.f;
            int ilo = r - 2 > 0 ? r - 2 : 0;
            int ihi = r < 3 ? r : 3;
            for (int i = ilo; i <= ihi; ++i) {
                int j = r - i;
                float wa = wr[j*3], wb = wr[j*3+1], wc = wr[j*3+2];
                acc[i][0] += wa*e[0] + wb*e[1] + wc*e[2];
                acc[i][1] += wa*e[1] + wb*e[2] + wc*e[3];
                acc[i][2] += wa*e[2] + wb*e[3] + wc*e[4];
                acc[i][3] += wa*e[3] + wb*e[4] + wc*e[5];
            }
        }
    }
    const float rs = 0.99999500003749968f;
    float sc = g[coff + c] * rs, bi = b[coff + c];
    unsigned short* outp = y + (((size_t)n * CoutTot + coff + c) * HH + h4) * WW + w4;
    #pragma unroll
    for (int i = 0; i < 4; ++i) {
        us4 o;
        o[0] = f2bf(fmaxf(acc[i][0] * sc + bi, 0.f));
        o[1] = f2bf(fmaxf(acc[i][1] * sc + bi, 0.f));
        o[2] = f2bf(fmaxf(acc[i][2] * sc + bi, 0.f));
        o[3] = f2bf(fmaxf(acc[i][3] * sc + bi, 0.f));
        *(us4*)(outp + i * WW) = o;
    }
}

// ---------------------------------------------------------------------------
// Pointwise 1x1 (Cin -> 128) + BN + ReLU via bf16 MFMA.
// Block 256 thr = 4 waves; tile 128 o x 128 px; wave = 64x64 (4x4 16-tiles).
// K-chunks of 32 staged in LDS: W[o][k], Z^T[px][k], row stride 56 bf16
// (16B-aligned b128 frag reads, ~2-way banks). MFMA 16x16x32_bf16:
//   A[m=lane&15][k=quad*8+j], B[n=lane&15][k=quad*8+j],
//   C/D col=lane&15 (px), row=quad*4+reg (o).          [m89/m120 layouts]
// ---------------------------------------------------------------------------
#define ZSTR 56

__global__ __launch_bounds__(256, 2) void pw_mfma_kernel(
    const unsigned short* __restrict__ zA, float* __restrict__ outA,
    const unsigned short* __restrict__ zB, float* __restrict__ outB,
    const float* __restrict__ Wp, const float* __restrict__ g,
    const float* __restrict__ b, int Cin)
{
    __shared__ unsigned short s_w[128*ZSTR];   // 14.3 KB
    __shared__ unsigned short s_z[128*ZSTR];   // 14.3 KB

    const int t  = threadIdx.x;
    const int n  = blockIdx.y;
    const int p0 = blockIdx.x * 128;
    const unsigned short* z = blockIdx.z ? zB : zA;
    float* out              = blockIdx.z ? outB : outA;

    const int wave = t >> 6, lane = t & 63;
    const int wo  = (wave & 1) * 64;
    const int wp_ = (wave >> 1) * 64;
    const int lm  = lane & 15, lq = lane >> 4;

    f32x4 acc[4][4];
    #pragma unroll
    for (int i = 0; i < 4; ++i)
        #pragma unroll
        for (int j = 0; j < 4; ++j)
            #pragma unroll
            for (int r = 0; r < 4; ++r) acc[i][j][r] = 0.f;

    const unsigned short* zn = z + (size_t)n * Cin * HWP;

    for (int kb = 0; kb < Cin; kb += 32) {
        // stage W chunk (f32 -> bf16): thread t: o = t>>1, cb = (t&1)*16
        {
            int o = t >> 1, cb = (t & 1) * 16;
            const float* wrow = Wp + o * Cin + kb + cb;
            unsigned short* dst = s_w + o * ZSTR + cb;
            #pragma unroll
            for (int i = 0; i < 16; i += 4) {
                float4 v = *(const float4*)(wrow + i);
                dst[i+0] = f2bf(v.x); dst[i+1] = f2bf(v.y);
                dst[i+2] = f2bf(v.z); dst[i+3] = f2bf(v.w);
            }
        }
        // stage Z chunk transposed: thread t: cc = t&31, pxg = (t>>5)*16
        {
            int cc = t & 31, pxg = (t >> 5) * 16;
            const unsigned short* src = zn + (size_t)(kb + cc) * HWP + p0 + pxg;
            uint4 a = *(const uint4*)src;
            uint4 b2 = *(const uint4*)(src + 8);
            unsigned v[8] = {a.x, a.y, a.z, a.w, b2.x, b2.y, b2.z, b2.w};
            #pragma unroll
            for (int i = 0; i < 8; ++i) {
                s_z[(pxg + 2*i    ) * ZSTR + cc] = (unsigned short)(v[i] & 0xffffu);
                s_z[(pxg + 2*i + 1) * ZSTR + cc] = (unsigned short)(v[i] >> 16);
            }
        }
        __syncthreads();

        bf16x8 af[4], bfv[4];
        #pragma unroll
        for (int i = 0; i < 4; ++i)
            af[i] = *(const bf16x8*)&s_w[(wo + i*16 + lm) * ZSTR + lq*8];
        #pragma unroll
        for (int j = 0; j < 4; ++j)
            bfv[j] = *(const bf16x8*)&s_z[(wp_ + j*16 + lm) * ZSTR + lq*8];
        #pragma unroll
        for (int i = 0; i < 4; ++i)
            #pragma unroll
            for (int j = 0; j < 4; ++j)
                acc[i][j] = __builtin_amdgcn_mfma_f32_16x16x32_bf16(
                    af[i], bfv[j], acc[i][j], 0, 0, 0);
        __syncthreads();
    }

    const float rs = 0.99999500003749968f;
    float* on = out + (size_t)n * 128 * HWP;
    #pragma unroll
    for (int i = 0; i < 4; ++i) {
        #pragma unroll
        for (int r = 0; r < 4; ++r) {
            int o = wo + i*16 + lq*4 + r;
            float sc = g[o] * rs, bi = b[o];
            #pragma unroll
            for (int j = 0; j < 4; ++j) {
                int px = wp_ + j*16 + lm;
                on[(size_t)o * HWP + p0 + px] =
                    fmaxf(acc[i][j][r] * sc + bi, 0.f);
            }
        }
    }
}

// ---------------------------------------------------------------------------
extern "C" void kernel_launch(void* const* d_in, const int* in_sizes, int n_in,
                              void* d_out, int out_size, void* d_ws, size_t ws_size,
                              hipStream_t stream) {
    const float* exemplar = (const float*)d_in[0];
    const float* query    = (const float*)d_in[1];
    const float* w_conv_e = (const float*)d_in[2];
    const float* w_gate1  = (const float*)d_in[3];
    const float* w_gate2  = (const float*)d_in[4];
    const float* dw1_w    = (const float*)d_in[5];
    const float* bn1a_g   = (const float*)d_in[6];
    const float* bn1a_b   = (const float*)d_in[7];
    const float* pw1_w    = (const float*)d_in[8];
    const float* bn1b_g   = (const float*)d_in[9];
    const float* bn1b_b   = (const float*)d_in[10];
    const float* dwf_w    = (const float*)d_in[11];
    const float* bnfa_g   = (const float*)d_in[12];
    const float* bnfa_b   = (const float*)d_in[13];
    const float* pwf_w    = (const float*)d_in[14];
    const float* bnfb_g   = (const float*)d_in[15];
    const float* bnfb_b   = (const float*)d_in[16];

    float* out = (float*)d_out;
    float* ws  = (float*)d_ws;
    const size_t SZ = (size_t)NN * CC * HWP;
    float* bufA = ws;                                  // x_e (f32) -> y_e (f32)
    float* bufB = ws + SZ;                             // x_q (f32) -> y_q (f32)
    unsigned short* zE  = (unsigned short*)(ws + 2*SZ);        // bf16, 33.5 MB
    unsigned short* zQ  = zE + SZ;                             // bf16, 33.5 MB
    unsigned short* T16 = (unsigned short*)(ws + 3*SZ);        // bf16 (N,256,H,W)

    // 1) fused attention + gating + residual (f32)
    attn_kernel<<<dim3(PHN * PHN, NN), 512, 0, stream>>>(
        exemplar, query, w_conv_e, w_gate1, w_gate2, bufA, bufB);

    // 2) dsconv #1 depthwise: f32 -> bf16 z
    dw2_kernel<<<8192, 256, 0, stream>>>(bufA, zE, bufB, zQ,
                                         dw1_w, bn1a_g, bn1a_b, 128, 0, 0);

    // 3) dsconv #1 pointwise (MFMA): bf16 z -> f32 y
    pw_mfma_kernel<<<dim3(128, NN, 2), 256, 0, stream>>>(
        zE, bufA, zQ, bufB, pw1_w, bn1b_g, bn1b_b, 128);

    // 4) final depthwise on concat: f32 -> bf16 T (N,256,H,W)
    dw2_kernel<<<8192, 256, 0, stream>>>(bufA, T16, bufB, T16,
                                         dwf_w, bnfa_g, bnfa_b, 256, 0, 128);

    // 5) final pointwise 256 -> 128 (MFMA): bf16 T -> f32 out
    pw_mfma_kernel<<<dim3(128, NN, 1), 256, 0, stream>>>(
        T16, out, (const unsigned short*)nullptr, (float*)nullptr,
        pwf_w, bnfb_g, bnfb_b, 256);
}

// Round 4
// 635.814 us; speedup vs baseline: 1.0739x; 1.0527x over previous
//
#include <hip/hip_runtime.h>
#include <hip/hip_bf16.h>

#define NN 8
#define CC 128
#define HH 128
#define WW 128
#define HWP (HH*WW)
#define KK 7
#define DD 49
#define NPH 31
#define NPATCH 961
#define PHN 19
#define PAD 52
#define PP2 (PAD*PAD)
#define XSTR 72   // bf16 row stride (144 B: 16B-aligned b128 frags, ~2-way banks)

typedef __attribute__((ext_vector_type(8))) short bf16x8;
typedef __attribute__((ext_vector_type(4))) float f32x4;
typedef __attribute__((ext_vector_type(4))) unsigned short us4;

__device__ __forceinline__ unsigned short f2bf(float f) {
    unsigned u = __builtin_bit_cast(unsigned, f);
    return (unsigned short)((u + 0x7FFFu + ((u >> 16) & 1u)) >> 16);   // RNE
}
__device__ __forceinline__ float bf2f(unsigned short u) {
    return __builtin_bit_cast(float, (unsigned)u << 16);
}

// ---------------------------------------------------------------------------
// Fused per-patch attention. Phases 1-5 fp32 math identical to the passing
// R2 version. Phase 6 (output GEMMs) now bf16 MFMA:
//   query_att[c][e]   = sum_d ex[c][d] * P1T[e][d]   (A=exh rows, B=P1T rows)
//   exemplar_att[c][d]= sum_e q [c][e] * P2 [d][e]   (A=qh rows,  B=P2 rows)
// ex/q converted in-place fp32->bf16 (reg snapshot + barrier), K padded 49->64
// with zeros on the A-side AND P pad cols zeroed (NaN-safe). P built directly
// in the MFMA-needed orientation (P1T / P2) as bf16. Gates read bf16 P.
// Residual is re-read from global at OUTPUT coords in phase 7 (required:
// LDS holds scrambled-channel stride-4 patch data, not output pixels).
// ---------------------------------------------------------------------------
__global__ __launch_bounds__(512, 4) void attn_kernel(
    const float* __restrict__ ex_g, const float* __restrict__ q_g,
    const float* __restrict__ Wce, const float* __restrict__ wg1,
    const float* __restrict__ wg2,
    float* __restrict__ xe, float* __restrict__ xq)
{
    __shared__ float s_ex[CC*PAD];
    __shared__ float s_q [CC*PAD];
    __shared__ float s_scr[CC*PAD];
    __shared__ float s_m1[PAD], s_l1[PAD], s_m2[PAD], s_l2[PAD];
    __shared__ float s_g1[PAD], s_g2[PAD], s_me[PAD], s_mq[PAD];

    const int t  = threadIdx.x;
    const int n  = blockIdx.y;
    const int ph = blockIdx.x / PHN;
    const int pw = blockIdx.x % PHN;
    const int pp = (ph * NPH + pw) * CC;

    const float* exn = ex_g + (size_t)n * CC * HWP;
    const float* qn  = q_g  + (size_t)n * CC * HWP;

    // ---- Phase 1: EX gather. Slot i = (c2, kh): one 7-float row; kh==7 zeroes pad.
    #pragma unroll
    for (int ii = 0; ii < 2; ++ii) {
        const int i  = t + ii*512;
        const int c2 = i >> 3, kh = i & 7;
        const int rem  = pp + c2;
        const int c_u  = rem / NPATCH;
        const int p_u  = rem - c_u * NPATCH;
        const int ph_u = p_u / NPH;
        const int pw_u = p_u - ph_u * NPH;
        float* de = &s_ex[c2*PAD + kh*KK];
        if (kh < KK) {
            const float* se = exn + ((c_u*HH + ph_u*4 + kh)*WW + pw_u*4);
            const float4 e4 = *(const float4*)se;       // 16B aligned (pw_u*4 floats)
            const float2 e2 = *(const float2*)(se + 4);
            const float  e1 = se[6];
            de[0]=e4.x; de[1]=e4.y; de[2]=e4.z; de[3]=e4.w;
            de[4]=e2.x; de[5]=e2.y; de[6]=e1;
        } else {
            de[0]=0.f; de[1]=0.f; de[2]=0.f;            // cols 49..51
        }
    }
    __syncthreads();

    // ---- Phase 2: ec = Wce @ ex on waves 1..7.5 ; Q gather on wave 0.
    if (t >= 64 && t < 480) {
        const int t2 = t - 64;
        const int eg_o = t2 / 13, eg_d = t2 - (t2/13)*13;
        const int o0 = eg_o*4, d0 = eg_d*4;
        float ac[4][4];
        #pragma unroll
        for (int i = 0; i < 4; ++i)
            #pragma unroll
            for (int j = 0; j < 4; ++j) ac[i][j] = 0.f;
        for (int k = 0; k < CC; k += 4) {
            float xm[4][4];
            #pragma unroll
            for (int kk = 0; kk < 4; ++kk) {
                float4 xv = *(const float4*)&s_ex[(k+kk)*PAD + d0];
                xm[kk][0]=xv.x; xm[kk][1]=xv.y; xm[kk][2]=xv.z; xm[kk][3]=xv.w;
            }
            #pragma unroll
            for (int i = 0; i < 4; ++i) {
                float4 wv = *(const float4*)&Wce[(o0+i)*CC + k];
                float wr[4] = {wv.x, wv.y, wv.z, wv.w};
                #pragma unroll
                for (int kk = 0; kk < 4; ++kk)
                    #pragma unroll
                    for (int j = 0; j < 4; ++j)
                        ac[i][j] = fmaf(wr[kk], xm[kk][j], ac[i][j]);
            }
        }
        #pragma unroll
        for (int i = 0; i < 4; ++i)
            *(float4*)&s_scr[(o0+i)*PAD + d0] =
                make_float4(ac[i][0], ac[i][1], ac[i][2], ac[i][3]);
    } else if (t < 64) {
        #pragma unroll 4
        for (int jj = 0; jj < 16; ++jj) {
            const int i  = t + jj*64;                   // covers [0,1024) exactly
            const int c2 = i >> 3, kh = i & 7;
            const int rem  = pp + c2;
            const int c_u  = rem / NPATCH;
            const int p_u  = rem - c_u * NPATCH;
            const int ph_u = p_u / NPH;
            const int pw_u = p_u - ph_u * NPH;
            float* dq = &s_q[c2*PAD + kh*KK];
            if (kh < KK) {
                const float* sq = qn + ((c_u*HH + ph_u*4 + kh)*WW + pw_u*4);
                const float4 q4 = *(const float4*)sq;
                const float2 q2 = *(const float2*)(sq + 4);
                const float  q1 = sq[6];
                dq[0]=q4.x; dq[1]=q4.y; dq[2]=q4.z; dq[3]=q4.w;
                dq[4]=q2.x; dq[5]=q2.y; dq[6]=q1;
            } else {
                dq[0]=0.f; dq[1]=0.f; dq[2]=0.f;
            }
        }
    }
    __syncthreads();

    // ---- Phase 3: A = ec^T q, 338 threads 4d x 2e; g1/g2 on spare threads.
    float aa[4][2];
    int ad0 = 0, ae0 = 0;
    if (t < 338) {
        int dg = t % 13, eg = t / 13;
        ad0 = dg*4; ae0 = eg*2;
        #pragma unroll
        for (int i = 0; i < 4; ++i) { aa[i][0] = 0.f; aa[i][1] = 0.f; }
        #pragma unroll 4
        for (int k = 0; k < CC; ++k) {
            float4 ev = *(const float4*)&s_scr[k*PAD + ad0];
            float2 qv = *(const float2*)&s_q [k*PAD + ae0];
            #pragma unroll
            for (int i = 0; i < 4; ++i) {
                float e = (i==0)?ev.x:(i==1)?ev.y:(i==2)?ev.z:ev.w;
                aa[i][0] = fmaf(e, qv.x, aa[i][0]);
                aa[i][1] = fmaf(e, qv.y, aa[i][1]);
            }
        }
    } else if (t >= 352 && t < 352 + DD) {
        int e = t - 352;
        float acc = 0.f;
        for (int c = 0; c < CC; ++c) acc = fmaf(wg1[c], s_q[c*PAD + e], acc);
        s_g1[e] = acc;
    } else if (t >= 416 && t < 416 + DD) {
        int d = t - 416;
        float acc = 0.f;
        for (int c = 0; c < CC; ++c) acc = fmaf(wg2[c], s_ex[c*PAD + d], acc);
        s_g2[d] = acc;
    }
    __syncthreads();
    if (t < 338) {
        #pragma unroll
        for (int i = 0; i < 4; ++i)
            *(float2*)&s_scr[(ad0+i)*PAD + ae0] = make_float2(aa[i][0], aa[i][1]);
    }
    __syncthreads();

    // ---- Phase 4: softmax stats (4 partial lanes/line + shfl_xor) and, in
    // parallel, register snapshot of s_ex/s_q for the in-place bf16 convert.
    float cex[13], cq[13];
    #pragma unroll
    for (int k = 0; k < 13; ++k) {          // 13*512 == CC*PAD exactly
        int i = t + k*512;
        cex[k] = s_ex[i];
        cq[k]  = s_q[i];
    }
    {
        const int sub  = t & 3;
        const int line = (t >> 2) & 63;
        const int lo   = sub * 13;
        float v[13];
        if (t < 256) {                      // set 1: per column e, over d
            if (line < DD) {
                #pragma unroll
                for (int j = 0; j < 13; ++j) {
                    int d = lo + j;
                    v[j] = (d < DD) ? s_scr[d*PAD + line] : -1e30f;
                }
                float m = v[0];
                #pragma unroll
                for (int j = 1; j < 13; ++j) m = fmaxf(m, v[j]);
                m = fmaxf(m, __shfl_xor(m, 1));
                m = fmaxf(m, __shfl_xor(m, 2));
                float l = 0.f;
                #pragma unroll
                for (int j = 0; j < 13; ++j) l += __expf(v[j] - m);  // sentinel -> 0
                l += __shfl_xor(l, 1);
                l += __shfl_xor(l, 2);
                if (sub == 0) { s_m1[line] = m; s_l1[line] = 1.f / l; }
            } else if (line < PAD && sub == 0) { s_m1[line] = 0.f; s_l1[line] = 0.f; }
        } else {                            // set 2: per row d, over e
            if (line < DD) {
                #pragma unroll
                for (int j = 0; j < 13; ++j) {
                    int e = lo + j;
                    v[j] = (e < DD) ? s_scr[line*PAD + e] : -1e30f;
                }
                float m = v[0];
                #pragma unroll
                for (int j = 1; j < 13; ++j) m = fmaxf(m, v[j]);
                m = fmaxf(m, __shfl_xor(m, 1));
                m = fmaxf(m, __shfl_xor(m, 2));
                float l = 0.f;
                #pragma unroll
                for (int j = 0; j < 13; ++j) l += __expf(v[j] - m);
                l += __shfl_xor(l, 1);
                l += __shfl_xor(l, 2);
                if (sub == 0) { s_m2[line] = m; s_l2[line] = 1.f / l; }
            } else if (line < PAD && sub == 0) { s_m2[line] = 0.f; s_l2[line] = 0.f; }
        }
    }
    __syncthreads();

    // ---- Phase 4.5: in-place bf16 conversion of ex/q (stride-72 rows, cols
    // 52..63 zeroed; 49..51 already zero) + P-value snapshot (needs stats).
    unsigned short* exh = (unsigned short*)s_ex;   // exh[c][d], [128][72]
    unsigned short* qh  = (unsigned short*)s_q;    // qh [c][e], [128][72]
    float p1v[6], p2v[6];
    #pragma unroll
    for (int k = 0; k < 13; ++k) {
        int i = t + k*512;
        int c = i / PAD, d = i - c*PAD;
        exh[c*XSTR + d] = f2bf(cex[k]);
        qh [c*XSTR + d] = f2bf(cq[k]);
    }
    for (int i = t; i < CC*12; i += 512) {          // zero cols 52..63
        int c = i / 12, d = 52 + (i - (i/12)*12);
        exh[c*XSTR + d] = 0;
        qh [c*XSTR + d] = 0;
    }
    #pragma unroll
    for (int k = 0; k < 6; ++k) {
        int i = t + k*512;
        if (i < PP2) {
            int d = i / PAD, e = i - d*PAD;
            float a = s_scr[i];
            p1v[k] = __expf(a - s_m1[e]) * s_l1[e];
            p2v[k] = __expf(a - s_m2[d]) * s_l2[d];
        }
    }
    __syncthreads();

    // ---- Phase 5: write P as bf16 in MFMA orientation + zero pad cols.
    // p2h[d][e] = B2[d][e]; p1t[e][d] = A1[d][e]. Rows >=49 are stale garbage
    // (reads safe, outputs discarded); k-cols 49..63 of rows <49 zeroed.
    unsigned short* p2h = (unsigned short*)s_scr;  // [64][72] (rows<49 valid)
    unsigned short* p1t = p2h + 64*XSTR;           // [64][72]
    #pragma unroll
    for (int k = 0; k < 6; ++k) {
        int i = t + k*512;
        if (i < PP2) {
            int d = i / PAD, e = i - d*PAD;
            if (d < DD && e < DD) {
                p2h[d*XSTR + e] = f2bf(p2v[k]);
                p1t[e*XSTR + d] = f2bf(p1v[k]);
            }
        }
    }
    for (int i = t; i < DD*15; i += 512) {          // zero cols 49..63, rows<49
        int r = i / 15, c2 = 49 + (i - (i/15)*15);
        p2h[r*XSTR + c2] = 0;
        p1t[r*XSTR + c2] = 0;
    }
    __syncthreads();

    // ---- Phase 6: MFMA output GEMMs (all 8 waves) + gate masks (98 lanes).
    // Wave w owns c-tile [w*16, w*16+16); 4 n-tiles cover e/d in [0,64).
    const int wv  = t >> 6, lane = t & 63;
    const int lm0 = lane & 15, lq = lane >> 4;
    const int crow = wv*16 + lm0;
    f32x4 accQ[4], accE[4];
    #pragma unroll
    for (int nt = 0; nt < 4; ++nt)
        #pragma unroll
        for (int r = 0; r < 4; ++r) { accQ[nt][r] = 0.f; accE[nt][r] = 0.f; }
    {
        bf16x8 ax[2], aq2[2];
        ax[0]  = *(const bf16x8*)&exh[crow*XSTR + lq*8];
        ax[1]  = *(const bf16x8*)&exh[crow*XSTR + 32 + lq*8];
        aq2[0] = *(const bf16x8*)&qh [crow*XSTR + lq*8];
        aq2[1] = *(const bf16x8*)&qh [crow*XSTR + 32 + lq*8];
        #pragma unroll
        for (int nt = 0; nt < 4; ++nt) {
            const int brow = nt*16 + lm0;
            #pragma unroll
            for (int ks = 0; ks < 2; ++ks) {
                bf16x8 b1 = *(const bf16x8*)&p1t[brow*XSTR + ks*32 + lq*8];
                bf16x8 b2 = *(const bf16x8*)&p2h[brow*XSTR + ks*32 + lq*8];
                accQ[nt] = __builtin_amdgcn_mfma_f32_16x16x32_bf16(
                    ax[ks],  b1, accQ[nt], 0, 0, 0);
                accE[nt] = __builtin_amdgcn_mfma_f32_16x16x32_bf16(
                    aq2[ks], b2, accE[nt], 0, 0, 0);
            }
        }
    }
    if (t < DD) {                                   // ex_mask[d] (wave 0)
        float a1 = 0.f;
        for (int e = 0; e < DD; ++e)
            a1 = fmaf(s_g1[e], bf2f(p2h[t*XSTR + e]), a1);
        s_me[t] = 1.f / (1.f + __expf(-a1));
    } else if (t >= 64 && t < 64 + DD) {            // q_mask[e] (wave 1)
        int e2 = t - 64;
        float a2 = 0.f;
        for (int d = 0; d < DD; ++d)
            a2 = fmaf(s_g2[d], bf2f(p1t[e2*XSTR + d]), a2);
        s_mq[e2] = 1.f / (1.f + __expf(-a2));
    }
    __syncthreads();

    // ---- Phase 6.5: stage att*mask to fp32 [c][PAD] layout for writeout.
    #pragma unroll
    for (int nt = 0; nt < 4; ++nt) {
        const int col = nt*16 + lm0;
        if (col < DD) {
            const float me_ = s_me[col], mq_ = s_mq[col];
            #pragma unroll
            for (int r = 0; r < 4; ++r) {
                const int c = wv*16 + lq*4 + r;
                s_ex[c*PAD + col] = accE[nt][r] * me_;
                s_q [c*PAD + col] = accQ[nt][r] * mq_;
            }
        }
    }
    __syncthreads();

    // ---- Phase 7: writeout, one 7-px row per slot; residual re-read from
    // global at OUTPUT coords (required; see header).
    {
        const size_t nbase = (size_t)n * CC * HWP;
        const int hb = ph*KK, wb = pw*KK;
        const int wlim = (WW - wb) < KK ? (WW - wb) : KK;
        #pragma unroll
        for (int ii = 0; ii < 2; ++ii) {
            const int i  = t + ii*512;
            const int c  = i >> 3, kh = i & 7;
            const int h  = hb + kh;
            if (kh < KK && h < HH) {
                const int li = (c*HH + h)*WW + wb;
                const float* sxe = &s_ex[c*PAD + kh*KK];
                const float* sxq = &s_q [c*PAD + kh*KK];
                if (wlim == KK) {
                    #pragma unroll
                    for (int kw = 0; kw < KK; ++kw) {
                        xe[nbase + li + kw] = sxe[kw] + exn[li + kw];
                        xq[nbase + li + kw] = sxq[kw] + qn [li + kw];
                    }
                } else {
                    for (int kw = 0; kw < wlim; ++kw) {
                        xe[nbase + li + kw] = sxe[kw] + exn[li + kw];
                        xq[nbase + li + kw] = sxq[kw] + qn [li + kw];
                    }
                }
            }
        }
    }
}

// ---------------------------------------------------------------------------
// Fused pair of depthwise 3x3 + BN + ReLU. f32 in, bf16 out (pw consumes it).
// ---------------------------------------------------------------------------
__global__ __launch_bounds__(256) void dw2_kernel(
    const float* __restrict__ xA, unsigned short* __restrict__ yA,
    const float* __restrict__ xB, unsigned short* __restrict__ yB,
    const float* __restrict__ wdw, const float* __restrict__ g,
    const float* __restrict__ b, int CoutTot, int coffA, int coffB)
{
    int bid = blockIdx.x;
    int sel = bid >> 12;
    int idx = (bid & 4095) * 256 + threadIdx.x;
    const float* x = sel ? xB : xA;
    unsigned short* y = sel ? yB : yA;
    int coff          = sel ? coffB : coffA;

    int w4 = (idx & 31) * 4;
    int h4 = ((idx >> 5) & 31) * 4;
    int nc = idx >> 10;
    int c  = nc & 127;
    int n  = nc >> 7;

    const float* wp = wdw + (coff + c) * 9;
    float wr[9];
    #pragma unroll
    for (int i = 0; i < 9; ++i) wr[i] = wp[i];

    const float* base = x + (size_t)nc * HWP;
    float acc[4][4];
    #pragma unroll
    for (int i = 0; i < 4; ++i)
        #pragma unroll
        for (int j = 0; j < 4; ++j) acc[i][j] = 0.f;

    #pragma unroll
    for (int r = 0; r < 6; ++r) {
        int hh = h4 - 1 + r;
        if (hh >= 0 && hh < HH) {
            const float* row = base + hh * WW + w4;
            float4 v = *(const float4*)row;
            float e[6];
            e[0] = (w4 > 0)   ? row[-1] : 0.f;
            e[1] = v.x; e[2] = v.y; e[3] = v.z; e[4] = v.w;
            e[5] = (w4 < 124) ? row[4]  : 0.f;
            int ilo = r - 2 > 0 ? r - 2 : 0;
            int ihi = r < 3 ? r : 3;
            for (int i = ilo; i <= ihi; ++i) {
                int j = r - i;
                float wa = wr[j*3], wb = wr[j*3+1], wc = wr[j*3+2];
                acc[i][0] += wa*e[0] + wb*e[1] + wc*e[2];
                acc[i][1] += wa*e[1] + wb*e[2] + wc*e[3];
                acc[i][2] += wa*e[2] + wb*e[3] + wc*e[4];
                acc[i][3] += wa*e[3] + wb*e[4] + wc*e[5];
            }
        }
    }
    const float rs = 0.99999500003749968f;
    float sc = g[coff + c] * rs, bi = b[coff + c];
    unsigned short* outp = y + (((size_t)n * CoutTot + coff + c) * HH + h4) * WW + w4;
    #pragma unroll
    for (int i = 0; i < 4; ++i) {
        us4 o;
        o[0] = f2bf(fmaxf(acc[i][0] * sc + bi, 0.f));
        o[1] = f2bf(fmaxf(acc[i][1] * sc + bi, 0.f));
        o[2] = f2bf(fmaxf(acc[i][2] * sc + bi, 0.f));
        o[3] = f2bf(fmaxf(acc[i][3] * sc + bi, 0.f));
        *(us4*)(outp + i * WW) = o;
    }
}

// ---------------------------------------------------------------------------
// Pointwise 1x1 (Cin -> 128) + BN + ReLU via bf16 MFMA.
// Block 256 thr = 4 waves; tile 128 o x 128 px; wave = 64x64 (4x4 16-tiles).
// K-chunks of 32 staged in LDS: W[o][k], Z^T[px][k], row stride 56 bf16
// (16B-aligned b128 frag reads, ~2-way banks). MFMA 16x16x32_bf16:
//   A[m=lane&15][k=quad*8+j], B[n=lane&15][k=quad*8+j],
//   C/D col=lane&15 (px), row=quad*4+reg (o).          [m89/m120 layouts]
// launch_bounds (256,3): cap VGPR ~170 so 3 blocks/CU can reside (LDS allows 5).
// ---------------------------------------------------------------------------
#define ZSTR 56

__global__ __launch_bounds__(256, 3) void pw_mfma_kernel(
    const unsigned short* __restrict__ zA, float* __restrict__ outA,
    const unsigned short* __restrict__ zB, float* __restrict__ outB,
    const float* __restrict__ Wp, const float* __restrict__ g,
    const float* __restrict__ b, int Cin)
{
    __shared__ unsigned short s_w[128*ZSTR];   // 14.3 KB
    __shared__ unsigned short s_z[128*ZSTR];   // 14.3 KB

    const int t  = threadIdx.x;
    const int n  = blockIdx.y;
    const int p0 = blockIdx.x * 128;
    const unsigned short* z = blockIdx.z ? zB : zA;
    float* out              = blockIdx.z ? outB : outA;

    const int wave = t >> 6, lane = t & 63;
    const int wo  = (wave & 1) * 64;
    const int wp_ = (wave >> 1) * 64;
    const int lm  = lane & 15, lq = lane >> 4;

    f32x4 acc[4][4];
    #pragma unroll
    for (int i = 0; i < 4; ++i)
        #pragma unroll
        for (int j = 0; j < 4; ++j)
            #pragma unroll
            for (int r = 0; r < 4; ++r) acc[i][j][r] = 0.f;

    const unsigned short* zn = z + (size_t)n * Cin * HWP;

    for (int kb = 0; kb < Cin; kb += 32) {
        // stage W chunk (f32 -> bf16): thread t: o = t>>1, cb = (t&1)*16
        {
            int o = t >> 1, cb = (t & 1) * 16;
            const float* wrow = Wp + o * Cin + kb + cb;
            unsigned short* dst = s_w + o * ZSTR + cb;
            #pragma unroll
            for (int i = 0; i < 16; i += 4) {
                float4 v = *(const float4*)(wrow + i);
                dst[i+0] = f2bf(v.x); dst[i+1] = f2bf(v.y);
                dst[i+2] = f2bf(v.z); dst[i+3] = f2bf(v.w);
            }
        }
        // stage Z chunk transposed: thread t: cc = t&31, pxg = (t>>5)*16
        {
            int cc = t & 31, pxg = (t >> 5) * 16;
            const unsigned short* src = zn + (size_t)(kb + cc) * HWP + p0 + pxg;
            uint4 a = *(const uint4*)src;
            uint4 b2 = *(const uint4*)(src + 8);
            unsigned v[8] = {a.x, a.y, a.z, a.w, b2.x, b2.y, b2.z, b2.w};
            #pragma unroll
            for (int i = 0; i < 8; ++i) {
                s_z[(pxg + 2*i    ) * ZSTR + cc] = (unsigned short)(v[i] & 0xffffu);
                s_z[(pxg + 2*i + 1) * ZSTR + cc] = (unsigned short)(v[i] >> 16);
            }
        }
        __syncthreads();

        bf16x8 af[4], bfv[4];
        #pragma unroll
        for (int i = 0; i < 4; ++i)
            af[i] = *(const bf16x8*)&s_w[(wo + i*16 + lm) * ZSTR + lq*8];
        #pragma unroll
        for (int j = 0; j < 4; ++j)
            bfv[j] = *(const bf16x8*)&s_z[(wp_ + j*16 + lm) * ZSTR + lq*8];
        #pragma unroll
        for (int i = 0; i < 4; ++i)
            #pragma unroll
            for (int j = 0; j < 4; ++j)
                acc[i][j] = __builtin_amdgcn_mfma_f32_16x16x32_bf16(
                    af[i], bfv[j], acc[i][j], 0, 0, 0);
        __syncthreads();
    }

    const float rs = 0.99999500003749968f;
    float* on = out + (size_t)n * 128 * HWP;
    #pragma unroll
    for (int i = 0; i < 4; ++i) {
        #pragma unroll
        for (int r = 0; r < 4; ++r) {
            int o = wo + i*16 + lq*4 + r;
            float sc = g[o] * rs, bi = b[o];
            #pragma unroll
            for (int j = 0; j < 4; ++j) {
                int px = wp_ + j*16 + lm;
                on[(size_t)o * HWP + p0 + px] =
                    fmaxf(acc[i][j][r] * sc + bi, 0.f);
            }
        }
    }
}

// ---------------------------------------------------------------------------
extern "C" void kernel_launch(void* const* d_in, const int* in_sizes, int n_in,
                              void* d_out, int out_size, void* d_ws, size_t ws_size,
                              hipStream_t stream) {
    const float* exemplar = (const float*)d_in[0];
    const float* query    = (const float*)d_in[1];
    const float* w_conv_e = (const float*)d_in[2];
    const float* w_gate1  = (const float*)d_in[3];
    const float* w_gate2  = (const float*)d_in[4];
    const float* dw1_w    = (const float*)d_in[5];
    const float* bn1a_g   = (const float*)d_in[6];
    const float* bn1a_b   = (const float*)d_in[7];
    const float* pw1_w    = (const float*)d_in[8];
    const float* bn1b_g   = (const float*)d_in[9];
    const float* bn1b_b   = (const float*)d_in[10];
    const float* dwf_w    = (const float*)d_in[11];
    const float* bnfa_g   = (const float*)d_in[12];
    const float* bnfa_b   = (const float*)d_in[13];
    const float* pwf_w    = (const float*)d_in[14];
    const float* bnfb_g   = (const float*)d_in[15];
    const float* bnfb_b   = (const float*)d_in[16];

    float* out = (float*)d_out;
    float* ws  = (float*)d_ws;
    const size_t SZ = (size_t)NN * CC * HWP;
    float* bufA = ws;                                  // x_e (f32) -> y_e (f32)
    float* bufB = ws + SZ;                             // x_q (f32) -> y_q (f32)
    unsigned short* zE  = (unsigned short*)(ws + 2*SZ);        // bf16, 33.5 MB
    unsigned short* zQ  = zE + SZ;                             // bf16, 33.5 MB
    unsigned short* T16 = (unsigned short*)(ws + 3*SZ);        // bf16 (N,256,H,W)

    // 1) fused attention + gating + residual (f32)
    attn_kernel<<<dim3(PHN * PHN, NN), 512, 0, stream>>>(
        exemplar, query, w_conv_e, w_gate1, w_gate2, bufA, bufB);

    // 2) dsconv #1 depthwise: f32 -> bf16 z
    dw2_kernel<<<8192, 256, 0, stream>>>(bufA, zE, bufB, zQ,
                                         dw1_w, bn1a_g, bn1a_b, 128, 0, 0);

    // 3) dsconv #1 pointwise (MFMA): bf16 z -> f32 y
    pw_mfma_kernel<<<dim3(128, NN, 2), 256, 0, stream>>>(
        zE, bufA, zQ, bufB, pw1_w, bn1b_g, bn1b_b, 128);

    // 4) final depthwise on concat: f32 -> bf16 T (N,256,H,W)
    dw2_kernel<<<8192, 256, 0, stream>>>(bufA, T16, bufB, T16,
                                         dwf_w, bnfa_g, bnfa_b, 256, 0, 128);

    // 5) final pointwise 256 -> 128 (MFMA): bf16 T -> f32 out
    pw_mfma_kernel<<<dim3(128, NN, 1), 256, 0, stream>>>(
        T16, out, (const unsigned short*)nullptr, (float*)nullptr,
        pwf_w, bnfb_g, bnfb_b, 256);
}

// Round 6
// 566.572 us; speedup vs baseline: 1.2052x; 1.1222x over previous
//
#include <hip/hip_runtime.h>
#include <hip/hip_bf16.h>

#define NN 8
#define CC 128
#define HH 128
#define WW 128
#define HWP (HH*WW)
#define KK 7
#define DD 49
#define NPH 31
#define NPATCH 961
#define PHN 19
#define PAD 52
#define PP2 (PAD*PAD)
#define XSTR 72   // bf16 row stride (144 B: 16B-aligned b128 frags, ~2-way banks)

typedef __attribute__((ext_vector_type(8))) short bf16x8;
typedef __attribute__((ext_vector_type(4))) float f32x4;
typedef __attribute__((ext_vector_type(4))) unsigned short us4;

__device__ __forceinline__ unsigned short f2bf(float f) {
    unsigned u = __builtin_bit_cast(unsigned, f);
    return (unsigned short)((u + 0x7FFFu + ((u >> 16) & 1u)) >> 16);   // RNE
}
__device__ __forceinline__ float bf2f(unsigned short u) {
    return __builtin_bit_cast(float, (unsigned)u << 16);
}

// ---------------------------------------------------------------------------
// Fused per-patch attention (R4-passing math). XCD-aware bijective patch
// swizzle. NOTE: pp (unfold flat-reshape base) lives in 31-stride patch
// space: pp = (ph*NPH + pw)*CC — NOT pid*CC (R5 bug, absmax 1.21).
// ---------------------------------------------------------------------------
__global__ __launch_bounds__(512, 4) void attn_kernel(
    const float* __restrict__ ex_g, const float* __restrict__ q_g,
    const float* __restrict__ Wce, const float* __restrict__ wg1,
    const float* __restrict__ wg2,
    float* __restrict__ xe, float* __restrict__ xq)
{
    __shared__ float s_ex[CC*PAD];
    __shared__ float s_q [CC*PAD];
    __shared__ float s_scr[CC*PAD];
    __shared__ float s_m1[PAD], s_l1[PAD], s_m2[PAD], s_l2[PAD];
    __shared__ float s_g1[PAD], s_g2[PAD], s_me[PAD], s_mq[PAD];

    const int t  = threadIdx.x;
    const int n  = blockIdx.y;
    // XCD-aware bijective swizzle of the 361-patch grid (8 XCDs, q=45, r=1):
    // xcd 0 -> pids [0,46), xcd k>=1 -> [46+(k-1)*45, 46+k*45). Bijective.
    const int bx  = blockIdx.x;
    const int xcd = bx & 7, j0 = bx >> 3;
    const int pid = (xcd == 0) ? j0 : (46 + (xcd - 1) * 45 + j0);
    const int ph = pid / PHN;
    const int pw = pid % PHN;
    const int pp = (ph * NPH + pw) * CC;   // 31-stride unfold space!

    const float* exn = ex_g + (size_t)n * CC * HWP;
    const float* qn  = q_g  + (size_t)n * CC * HWP;

    // ---- Phase 1: EX gather. Slot i = (c2, kh): one 7-float row; kh==7 zeroes pad.
    #pragma unroll
    for (int ii = 0; ii < 2; ++ii) {
        const int i  = t + ii*512;
        const int c2 = i >> 3, kh = i & 7;
        const int rem  = pp + c2;
        const int c_u  = rem / NPATCH;
        const int p_u  = rem - c_u * NPATCH;
        const int ph_u = p_u / NPH;
        const int pw_u = p_u - ph_u * NPH;
        float* de = &s_ex[c2*PAD + kh*KK];
        if (kh < KK) {
            const float* se = exn + ((c_u*HH + ph_u*4 + kh)*WW + pw_u*4);
            const float4 e4 = *(const float4*)se;       // 16B aligned (pw_u*4 floats)
            const float2 e2 = *(const float2*)(se + 4);
            const float  e1 = se[6];
            de[0]=e4.x; de[1]=e4.y; de[2]=e4.z; de[3]=e4.w;
            de[4]=e2.x; de[5]=e2.y; de[6]=e1;
        } else {
            de[0]=0.f; de[1]=0.f; de[2]=0.f;            // cols 49..51
        }
    }
    __syncthreads();

    // ---- Phase 2: ec = Wce @ ex on waves 1..7.5 ; Q gather on wave 0.
    if (t >= 64 && t < 480) {
        const int t2 = t - 64;
        const int eg_o = t2 / 13, eg_d = t2 - (t2/13)*13;
        const int o0 = eg_o*4, d0 = eg_d*4;
        float ac[4][4];
        #pragma unroll
        for (int i = 0; i < 4; ++i)
            #pragma unroll
            for (int j = 0; j < 4; ++j) ac[i][j] = 0.f;
        for (int k = 0; k < CC; k += 4) {
            float xm[4][4];
            #pragma unroll
            for (int kk = 0; kk < 4; ++kk) {
                float4 xv = *(const float4*)&s_ex[(k+kk)*PAD + d0];
                xm[kk][0]=xv.x; xm[kk][1]=xv.y; xm[kk][2]=xv.z; xm[kk][3]=xv.w;
            }
            #pragma unroll
            for (int i = 0; i < 4; ++i) {
                float4 wv = *(const float4*)&Wce[(o0+i)*CC + k];
                float wr[4] = {wv.x, wv.y, wv.z, wv.w};
                #pragma unroll
                for (int kk = 0; kk < 4; ++kk)
                    #pragma unroll
                    for (int j = 0; j < 4; ++j)
                        ac[i][j] = fmaf(wr[kk], xm[kk][j], ac[i][j]);
            }
        }
        #pragma unroll
        for (int i = 0; i < 4; ++i)
            *(float4*)&s_scr[(o0+i)*PAD + d0] =
                make_float4(ac[i][0], ac[i][1], ac[i][2], ac[i][3]);
    } else if (t < 64) {
        #pragma unroll 4
        for (int jj = 0; jj < 16; ++jj) {
            const int i  = t + jj*64;                   // covers [0,1024) exactly
            const int c2 = i >> 3, kh = i & 7;
            const int rem  = pp + c2;
            const int c_u  = rem / NPATCH;
            const int p_u  = rem - c_u * NPATCH;
            const int ph_u = p_u / NPH;
            const int pw_u = p_u - ph_u * NPH;
            float* dq = &s_q[c2*PAD + kh*KK];
            if (kh < KK) {
                const float* sq = qn + ((c_u*HH + ph_u*4 + kh)*WW + pw_u*4);
                const float4 q4 = *(const float4*)sq;
                const float2 q2 = *(const float2*)(sq + 4);
                const float  q1 = sq[6];
                dq[0]=q4.x; dq[1]=q4.y; dq[2]=q4.z; dq[3]=q4.w;
                dq[4]=q2.x; dq[5]=q2.y; dq[6]=q1;
            } else {
                dq[0]=0.f; dq[1]=0.f; dq[2]=0.f;
            }
        }
    }
    __syncthreads();

    // ---- Phase 3: A = ec^T q, 338 threads 4d x 2e; g1/g2 on spare threads.
    float aa[4][2];
    int ad0 = 0, ae0 = 0;
    if (t < 338) {
        int dg = t % 13, eg = t / 13;
        ad0 = dg*4; ae0 = eg*2;
        #pragma unroll
        for (int i = 0; i < 4; ++i) { aa[i][0] = 0.f; aa[i][1] = 0.f; }
        #pragma unroll 4
        for (int k = 0; k < CC; ++k) {
            float4 ev = *(const float4*)&s_scr[k*PAD + ad0];
            float2 qv = *(const float2*)&s_q [k*PAD + ae0];
            #pragma unroll
            for (int i = 0; i < 4; ++i) {
                float e = (i==0)?ev.x:(i==1)?ev.y:(i==2)?ev.z:ev.w;
                aa[i][0] = fmaf(e, qv.x, aa[i][0]);
                aa[i][1] = fmaf(e, qv.y, aa[i][1]);
            }
        }
    } else if (t >= 352 && t < 352 + DD) {
        int e = t - 352;
        float acc = 0.f;
        for (int c = 0; c < CC; ++c) acc = fmaf(wg1[c], s_q[c*PAD + e], acc);
        s_g1[e] = acc;
    } else if (t >= 416 && t < 416 + DD) {
        int d = t - 416;
        float acc = 0.f;
        for (int c = 0; c < CC; ++c) acc = fmaf(wg2[c], s_ex[c*PAD + d], acc);
        s_g2[d] = acc;
    }
    __syncthreads();
    if (t < 338) {
        #pragma unroll
        for (int i = 0; i < 4; ++i)
            *(float2*)&s_scr[(ad0+i)*PAD + ae0] = make_float2(aa[i][0], aa[i][1]);
    }
    __syncthreads();

    // ---- Phase 4: softmax stats (4 partial lanes/line + shfl_xor) and, in
    // parallel, register snapshot of s_ex/s_q for the in-place bf16 convert.
    float cex[13], cq[13];
    #pragma unroll
    for (int k = 0; k < 13; ++k) {          // 13*512 == CC*PAD exactly
        int i = t + k*512;
        cex[k] = s_ex[i];
        cq[k]  = s_q[i];
    }
    {
        const int sub  = t & 3;
        const int line = (t >> 2) & 63;
        const int lo   = sub * 13;
        float v[13];
        if (t < 256) {                      // set 1: per column e, over d
            if (line < DD) {
                #pragma unroll
                for (int j = 0; j < 13; ++j) {
                    int d = lo + j;
                    v[j] = (d < DD) ? s_scr[d*PAD + line] : -1e30f;
                }
                float m = v[0];
                #pragma unroll
                for (int j = 1; j < 13; ++j) m = fmaxf(m, v[j]);
                m = fmaxf(m, __shfl_xor(m, 1));
                m = fmaxf(m, __shfl_xor(m, 2));
                float l = 0.f;
                #pragma unroll
                for (int j = 0; j < 13; ++j) l += __expf(v[j] - m);  // sentinel -> 0
                l += __shfl_xor(l, 1);
                l += __shfl_xor(l, 2);
                if (sub == 0) { s_m1[line] = m; s_l1[line] = 1.f / l; }
            } else if (line < PAD && sub == 0) { s_m1[line] = 0.f; s_l1[line] = 0.f; }
        } else {                            // set 2: per row d, over e
            if (line < DD) {
                #pragma unroll
                for (int j = 0; j < 13; ++j) {
                    int e = lo + j;
                    v[j] = (e < DD) ? s_scr[line*PAD + e] : -1e30f;
                }
                float m = v[0];
                #pragma unroll
                for (int j = 1; j < 13; ++j) m = fmaxf(m, v[j]);
                m = fmaxf(m, __shfl_xor(m, 1));
                m = fmaxf(m, __shfl_xor(m, 2));
                float l = 0.f;
                #pragma unroll
                for (int j = 0; j < 13; ++j) l += __expf(v[j] - m);
                l += __shfl_xor(l, 1);
                l += __shfl_xor(l, 2);
                if (sub == 0) { s_m2[line] = m; s_l2[line] = 1.f / l; }
            } else if (line < PAD && sub == 0) { s_m2[line] = 0.f; s_l2[line] = 0.f; }
        }
    }
    __syncthreads();

    // ---- Phase 4.5: in-place bf16 conversion of ex/q (stride-72 rows, cols
    // 52..63 zeroed; 49..51 already zero) + P-value snapshot (needs stats).
    unsigned short* exh = (unsigned short*)s_ex;   // exh[c][d], [128][72]
    unsigned short* qh  = (unsigned short*)s_q;    // qh [c][e], [128][72]
    float p1v[6], p2v[6];
    #pragma unroll
    for (int k = 0; k < 13; ++k) {
        int i = t + k*512;
        int c = i / PAD, d = i - c*PAD;
        exh[c*XSTR + d] = f2bf(cex[k]);
        qh [c*XSTR + d] = f2bf(cq[k]);
    }
    for (int i = t; i < CC*12; i += 512) {          // zero cols 52..63
        int c = i / 12, d = 52 + (i - (i/12)*12);
        exh[c*XSTR + d] = 0;
        qh [c*XSTR + d] = 0;
    }
    #pragma unroll
    for (int k = 0; k < 6; ++k) {
        int i = t + k*512;
        if (i < PP2) {
            int d = i / PAD, e = i - d*PAD;
            float a = s_scr[i];
            p1v[k] = __expf(a - s_m1[e]) * s_l1[e];
            p2v[k] = __expf(a - s_m2[d]) * s_l2[d];
        }
    }
    __syncthreads();

    // ---- Phase 5: write P as bf16 in MFMA orientation + zero pad cols.
    unsigned short* p2h = (unsigned short*)s_scr;  // [64][72] (rows<49 valid)
    unsigned short* p1t = p2h + 64*XSTR;           // [64][72]
    #pragma unroll
    for (int k = 0; k < 6; ++k) {
        int i = t + k*512;
        if (i < PP2) {
            int d = i / PAD, e = i - d*PAD;
            if (d < DD && e < DD) {
                p2h[d*XSTR + e] = f2bf(p2v[k]);
                p1t[e*XSTR + d] = f2bf(p1v[k]);
            }
        }
    }
    for (int i = t; i < DD*15; i += 512) {          // zero cols 49..63, rows<49
        int r = i / 15, c2 = 49 + (i - (i/15)*15);
        p2h[r*XSTR + c2] = 0;
        p1t[r*XSTR + c2] = 0;
    }
    __syncthreads();

    // ---- Phase 6: MFMA output GEMMs (all 8 waves) + gate masks (98 lanes).
    const int wv  = t >> 6, lane = t & 63;
    const int lm0 = lane & 15, lq = lane >> 4;
    const int crow = wv*16 + lm0;
    f32x4 accQ[4], accE[4];
    #pragma unroll
    for (int nt = 0; nt < 4; ++nt)
        #pragma unroll
        for (int r = 0; r < 4; ++r) { accQ[nt][r] = 0.f; accE[nt][r] = 0.f; }
    {
        bf16x8 ax[2], aq2[2];
        ax[0]  = *(const bf16x8*)&exh[crow*XSTR + lq*8];
        ax[1]  = *(const bf16x8*)&exh[crow*XSTR + 32 + lq*8];
        aq2[0] = *(const bf16x8*)&qh [crow*XSTR + lq*8];
        aq2[1] = *(const bf16x8*)&qh [crow*XSTR + 32 + lq*8];
        #pragma unroll
        for (int nt = 0; nt < 4; ++nt) {
            const int brow = nt*16 + lm0;
            #pragma unroll
            for (int ks = 0; ks < 2; ++ks) {
                bf16x8 b1 = *(const bf16x8*)&p1t[brow*XSTR + ks*32 + lq*8];
                bf16x8 b2 = *(const bf16x8*)&p2h[brow*XSTR + ks*32 + lq*8];
                accQ[nt] = __builtin_amdgcn_mfma_f32_16x16x32_bf16(
                    ax[ks],  b1, accQ[nt], 0, 0, 0);
                accE[nt] = __builtin_amdgcn_mfma_f32_16x16x32_bf16(
                    aq2[ks], b2, accE[nt], 0, 0, 0);
            }
        }
    }
    if (t < DD) {                                   // ex_mask[d] (wave 0)
        float a1 = 0.f;
        for (int e = 0; e < DD; ++e)
            a1 = fmaf(s_g1[e], bf2f(p2h[t*XSTR + e]), a1);
        s_me[t] = 1.f / (1.f + __expf(-a1));
    } else if (t >= 64 && t < 64 + DD) {            // q_mask[e] (wave 1)
        int e2 = t - 64;
        float a2 = 0.f;
        for (int d = 0; d < DD; ++d)
            a2 = fmaf(s_g2[d], bf2f(p1t[e2*XSTR + d]), a2);
        s_mq[e2] = 1.f / (1.f + __expf(-a2));
    }
    __syncthreads();

    // ---- Phase 6.5: stage att*mask to fp32 [c][PAD] layout for writeout.
    #pragma unroll
    for (int nt = 0; nt < 4; ++nt) {
        const int col = nt*16 + lm0;
        if (col < DD) {
            const float me_ = s_me[col], mq_ = s_mq[col];
            #pragma unroll
            for (int r = 0; r < 4; ++r) {
                const int c = wv*16 + lq*4 + r;
                s_ex[c*PAD + col] = accE[nt][r] * me_;
                s_q [c*PAD + col] = accQ[nt][r] * mq_;
            }
        }
    }
    __syncthreads();

    // ---- Phase 7: writeout, one 7-px row per slot; residual re-read from
    // global at OUTPUT coords (required: LDS holds scrambled stride-4 data).
    {
        const size_t nbase = (size_t)n * CC * HWP;
        const int hb = ph*KK, wb = pw*KK;
        const int wlim = (WW - wb) < KK ? (WW - wb) : KK;
        #pragma unroll
        for (int ii = 0; ii < 2; ++ii) {
            const int i  = t + ii*512;
            const int c  = i >> 3, kh = i & 7;
            const int h  = hb + kh;
            if (kh < KK && h < HH) {
                const int li = (c*HH + h)*WW + wb;
                const float* sxe = &s_ex[c*PAD + kh*KK];
                const float* sxq = &s_q [c*PAD + kh*KK];
                if (wlim == KK) {
                    #pragma unroll
                    for (int kw = 0; kw < KK; ++kw) {
                        xe[nbase + li + kw] = sxe[kw] + exn[li + kw];
                        xq[nbase + li + kw] = sxq[kw] + qn [li + kw];
                    }
                } else {
                    for (int kw = 0; kw < wlim; ++kw) {
                        xe[nbase + li + kw] = sxe[kw] + exn[li + kw];
                        xq[nbase + li + kw] = sxq[kw] + qn [li + kw];
                    }
                }
            }
        }
    }
}

// ---------------------------------------------------------------------------
// Fused pair of depthwise 3x3 + BN + ReLU. f32 OR bf16 input (in16 flag,
// wave-uniform branch); bf16 out (pw consumes it).
// ---------------------------------------------------------------------------
__global__ __launch_bounds__(256) void dw2_kernel(
    const float* __restrict__ xA, unsigned short* __restrict__ yA,
    const float* __restrict__ xB, unsigned short* __restrict__ yB,
    const float* __restrict__ wdw, const float* __restrict__ g,
    const float* __restrict__ b, int CoutTot, int coffA, int coffB, int in16)
{
    int bid = blockIdx.x;
    int sel = bid >> 12;
    int idx = (bid & 4095) * 256 + threadIdx.x;
    const float* x = sel ? xB : xA;
    unsigned short* y = sel ? yB : yA;
    int coff          = sel ? coffB : coffA;

    int w4 = (idx & 31) * 4;
    int h4 = ((idx >> 5) & 31) * 4;
    int nc = idx >> 10;
    int c  = nc & 127;
    int n  = nc >> 7;

    const float* wp = wdw + (coff + c) * 9;
    float wr[9];
    #pragma unroll
    for (int i = 0; i < 9; ++i) wr[i] = wp[i];

    const float*          base  = x + (size_t)nc * HWP;
    const unsigned short* baseh = (const unsigned short*)x + (size_t)nc * HWP;
    float acc[4][4];
    #pragma unroll
    for (int i = 0; i < 4; ++i)
        #pragma unroll
        for (int j = 0; j < 4; ++j) acc[i][j] = 0.f;

    #pragma unroll
    for (int r = 0; r < 6; ++r) {
        int hh = h4 - 1 + r;
        if (hh >= 0 && hh < HH) {
            float e[6];
            if (in16) {
                const unsigned short* row = baseh + hh * WW + w4;
                us4 v = *(const us4*)row;
                e[0] = (w4 > 0)   ? bf2f(row[-1]) : 0.f;
                e[1] = bf2f(v[0]); e[2] = bf2f(v[1]);
                e[3] = bf2f(v[2]); e[4] = bf2f(v[3]);
                e[5] = (w4 < 124) ? bf2f(row[4])  : 0.f;
            } else {
                const float* row = base + hh * WW + w4;
                float4 v = *(const float4*)row;
                e[0] = (w4 > 0)   ? row[-1] : 0.f;
                e[1] = v.x; e[2] = v.y; e[3] = v.z; e[4] = v.w;
                e[5] = (w4 < 124) ? row[4]  : 0.f;
            }
            int ilo = r - 2 > 0 ? r - 2 : 0;
            int ihi = r < 3 ? r : 3;
            for (int i = ilo; i <= ihi; ++i) {
                int j = r - i;
                float wa = wr[j*3], wb = wr[j*3+1], wc = wr[j*3+2];
                acc[i][0] += wa*e[0] + wb*e[1] + wc*e[2];
                acc[i][1] += wa*e[1] + wb*e[2] + wc*e[3];
                acc[i][2] += wa*e[2] + wb*e[3] + wc*e[4];
                acc[i][3] += wa*e[3] + wb*e[4] + wc*e[5];
            }
        }
    }
    const float rs = 0.99999500003749968f;
    float sc = g[coff + c] * rs, bi = b[coff + c];
    unsigned short* outp = y + (((size_t)n * CoutTot + coff + c) * HH + h4) * WW + w4;
    #pragma unroll
    for (int i = 0; i < 4; ++i) {
        us4 o;
        o[0] = f2bf(fmaxf(acc[i][0] * sc + bi, 0.f));
        o[1] = f2bf(fmaxf(acc[i][1] * sc + bi, 0.f));
        o[2] = f2bf(fmaxf(acc[i][2] * sc + bi, 0.f));
        o[3] = f2bf(fmaxf(acc[i][3] * sc + bi, 0.f));
        *(us4*)(outp + i * WW) = o;
    }
}

// ---------------------------------------------------------------------------
// Pointwise 1x1 (Cin -> 128) + BN + ReLU via bf16 MFMA.
// obf flag: output bf16 (intermediate y) or f32 (final out).
// ---------------------------------------------------------------------------
#define ZSTR 56

__global__ __launch_bounds__(256, 3) void pw_mfma_kernel(
    const unsigned short* __restrict__ zA, float* __restrict__ outA,
    const unsigned short* __restrict__ zB, float* __restrict__ outB,
    const float* __restrict__ Wp, const float* __restrict__ g,
    const float* __restrict__ b, int Cin, int obf)
{
    __shared__ unsigned short s_w[128*ZSTR];   // 14.3 KB
    __shared__ unsigned short s_z[128*ZSTR];   // 14.3 KB

    const int t  = threadIdx.x;
    const int n  = blockIdx.y;
    const int p0 = blockIdx.x * 128;
    const unsigned short* z = blockIdx.z ? zB : zA;
    float* out              = blockIdx.z ? outB : outA;

    const int wave = t >> 6, lane = t & 63;
    const int wo  = (wave & 1) * 64;
    const int wp_ = (wave >> 1) * 64;
    const int lm  = lane & 15, lq = lane >> 4;

    f32x4 acc[4][4];
    #pragma unroll
    for (int i = 0; i < 4; ++i)
        #pragma unroll
        for (int j = 0; j < 4; ++j)
            #pragma unroll
            for (int r = 0; r < 4; ++r) acc[i][j][r] = 0.f;

    const unsigned short* zn = z + (size_t)n * Cin * HWP;

    for (int kb = 0; kb < Cin; kb += 32) {
        // stage W chunk (f32 -> bf16): thread t: o = t>>1, cb = (t&1)*16
        {
            int o = t >> 1, cb = (t & 1) * 16;
            const float* wrow = Wp + o * Cin + kb + cb;
            unsigned short* dst = s_w + o * ZSTR + cb;
            #pragma unroll
            for (int i = 0; i < 16; i += 4) {
                float4 v = *(const float4*)(wrow + i);
                dst[i+0] = f2bf(v.x); dst[i+1] = f2bf(v.y);
                dst[i+2] = f2bf(v.z); dst[i+3] = f2bf(v.w);
            }
        }
        // stage Z chunk transposed: thread t: cc = t&31, pxg = (t>>5)*16
        {
            int cc = t & 31, pxg = (t >> 5) * 16;
            const unsigned short* src = zn + (size_t)(kb + cc) * HWP + p0 + pxg;
            uint4 a = *(const uint4*)src;
            uint4 b2 = *(const uint4*)(src + 8);
            unsigned v[8] = {a.x, a.y, a.z, a.w, b2.x, b2.y, b2.z, b2.w};
            #pragma unroll
            for (int i = 0; i < 8; ++i) {
                s_z[(pxg + 2*i    ) * ZSTR + cc] = (unsigned short)(v[i] & 0xffffu);
                s_z[(pxg + 2*i + 1) * ZSTR + cc] = (unsigned short)(v[i] >> 16);
            }
        }
        __syncthreads();

        bf16x8 af[4], bfv[4];
        #pragma unroll
        for (int i = 0; i < 4; ++i)
            af[i] = *(const bf16x8*)&s_w[(wo + i*16 + lm) * ZSTR + lq*8];
        #pragma unroll
        for (int j = 0; j < 4; ++j)
            bfv[j] = *(const bf16x8*)&s_z[(wp_ + j*16 + lm) * ZSTR + lq*8];
        #pragma unroll
        for (int i = 0; i < 4; ++i)
            #pragma unroll
            for (int j = 0; j < 4; ++j)
                acc[i][j] = __builtin_amdgcn_mfma_f32_16x16x32_bf16(
                    af[i], bfv[j], acc[i][j], 0, 0, 0);
        __syncthreads();
    }

    const float rs = 0.99999500003749968f;
    if (obf) {
        unsigned short* on = (unsigned short*)out + (size_t)n * 128 * HWP;
        #pragma unroll
        for (int i = 0; i < 4; ++i) {
            #pragma unroll
            for (int r = 0; r < 4; ++r) {
                int o = wo + i*16 + lq*4 + r;
                float sc = g[o] * rs, bi = b[o];
                #pragma unroll
                for (int j = 0; j < 4; ++j) {
                    int px = wp_ + j*16 + lm;
                    on[(size_t)o * HWP + p0 + px] =
                        f2bf(fmaxf(acc[i][j][r] * sc + bi, 0.f));
                }
            }
        }
    } else {
        float* on = out + (size_t)n * 128 * HWP;
        #pragma unroll
        for (int i = 0; i < 4; ++i) {
            #pragma unroll
            for (int r = 0; r < 4; ++r) {
                int o = wo + i*16 + lq*4 + r;
                float sc = g[o] * rs, bi = b[o];
                #pragma unroll
                for (int j = 0; j < 4; ++j) {
                    int px = wp_ + j*16 + lm;
                    on[(size_t)o * HWP + p0 + px] =
                        fmaxf(acc[i][j][r] * sc + bi, 0.f);
                }
            }
        }
    }
}

// ---------------------------------------------------------------------------
extern "C" void kernel_launch(void* const* d_in, const int* in_sizes, int n_in,
                              void* d_out, int out_size, void* d_ws, size_t ws_size,
                              hipStream_t stream) {
    const float* exemplar = (const float*)d_in[0];
    const float* query    = (const float*)d_in[1];
    const float* w_conv_e = (const float*)d_in[2];
    const float* w_gate1  = (const float*)d_in[3];
    const float* w_gate2  = (const float*)d_in[4];
    const float* dw1_w    = (const float*)d_in[5];
    const float* bn1a_g   = (const float*)d_in[6];
    const float* bn1a_b   = (const float*)d_in[7];
    const float* pw1_w    = (const float*)d_in[8];
    const float* bn1b_g   = (const float*)d_in[9];
    const float* bn1b_b   = (const float*)d_in[10];
    const float* dwf_w    = (const float*)d_in[11];
    const float* bnfa_g   = (const float*)d_in[12];
    const float* bnfa_b   = (const float*)d_in[13];
    const float* pwf_w    = (const float*)d_in[14];
    const float* bnfb_g   = (const float*)d_in[15];
    const float* bnfb_b   = (const float*)d_in[16];

    float* out = (float*)d_out;
    float* ws  = (float*)d_ws;
    const size_t SZ = (size_t)NN * CC * HWP;
    float* bufA = ws;                                  // attn x_e (f32); later y16 overlay
    float* bufB = ws + SZ;                             // attn x_q (f32)
    unsigned short* zE  = (unsigned short*)(ws + 2*SZ);        // bf16, 33.5 MB
    unsigned short* zQ  = zE + SZ;                             // bf16, 33.5 MB
    unsigned short* T16 = (unsigned short*)(ws + 3*SZ);        // bf16 (N,256,H,W)
    // y_e/y_q bf16 overlay the bufA region (dead after dw#1 reads it):
    unsigned short* yE16 = (unsigned short*)bufA;              // SZ bf16
    unsigned short* yQ16 = yE16 + SZ;                          // SZ bf16

    // 1) fused attention + gating + residual (f32)
    attn_kernel<<<dim3(PHN * PHN, NN), 512, 0, stream>>>(
        exemplar, query, w_conv_e, w_gate1, w_gate2, bufA, bufB);

    // 2) dsconv #1 depthwise: f32 -> bf16 z
    dw2_kernel<<<8192, 256, 0, stream>>>(bufA, zE, bufB, zQ,
                                         dw1_w, bn1a_g, bn1a_b, 128, 0, 0, 0);

    // 3) dsconv #1 pointwise (MFMA): bf16 z -> bf16 y (overlays bufA region)
    pw_mfma_kernel<<<dim3(128, NN, 2), 256, 0, stream>>>(
        zE, (float*)yE16, zQ, (float*)yQ16, pw1_w, bn1b_g, bn1b_b, 128, 1);

    // 4) final depthwise on concat: bf16 y -> bf16 T (N,256,H,W)
    dw2_kernel<<<8192, 256, 0, stream>>>((const float*)yE16, T16,
                                         (const float*)yQ16, T16,
                                         dwf_w, bnfa_g, bnfa_b, 256, 0, 128, 1);

    // 5) final pointwise 256 -> 128 (MFMA): bf16 T -> f32 out
    pw_mfma_kernel<<<dim3(128, NN, 1), 256, 0, stream>>>(
        T16, out, (const unsigned short*)nullptr, (float*)nullptr,
        pwf_w, bnfb_g, bnfb_b, 256, 0);
}